// Round 2
// baseline (549.054 us; speedup 1.0000x reference)
//
#include <hip/hip_runtime.h>
#include <math.h>

// Problem shape (fixed by reference): B=256 users, F=64 friends/user,
// L=50 history, D=128 dims, N=B*F=16384 friend rows.
// DTYPE NOTE (round-1 post-mortem): all float tensors are fp32 on the wire
// (reference dtype), NOT bf16 — reading them as bf16 produced NaN garbage.
constexpr int B_ = 256;
constexpr int F_ = 64;
constexpr int L_ = 50;
constexpr int D_ = 128;
constexpr int N_ = B_ * F_;

typedef float f32x4 __attribute__((ext_vector_type(4)));

__global__ __launch_bounds__(256) void FRIENDATTN_67680094650650_kernel(
    const float* __restrict__ x,      // [N, L, D] fp32
    const float* __restrict__ selfx,  // [B, D]    fp32
    const int* __restrict__ mask,     // [N, L]    int32 0/1
    float* __restrict__ out)          // [N, D]    fp32
{
    // Flat [L][D] tile, stride 128 words. All three phases are designed so
    // 128-word stride is conflict-free (see per-phase notes).
    __shared__ __align__(16) float xs[L_ * D_];  // 25600 B -> 6 blocks/CU
    __shared__ float score_s[L_];
    __shared__ float w_s[L_];

    const int tid = threadIdx.x;
    const int n = blockIdx.x;
    const int b = n >> 6;  // n / F_

    // ---- self fragment in registers: thread's fixed 4-dim chunk ----
    const int dq = (tid & 31) * 4;  // d-offset, lanes 0..31 cover d=0..127
    const f32x4 sf = *(const f32x4*)(selfx + b * D_ + dq);

    // ---- stage x row into LDS: flat copy, 1600 float4 chunks ----
    // Coalesced global reads; LDS writes contiguous across lanes -> no conflicts.
    const float* xrow = x + (size_t)n * (L_ * D_);
    for (int c = tid; c < (L_ * D_) / 4; c += 256) {
        *(f32x4*)(xs + c * 4) = *(const f32x4*)(xrow + c * 4);
    }
    __syncthreads();

    // ---- scores: 32 lanes cooperate per l-row ----
    // Lanes (t&31)=0..31 read one full contiguous 128-word row as float4 ->
    // each bank receives exactly 8 word-requests per wave instr (optimal).
    {
        const int lsub = tid >> 5;  // 0..7: which l this 32-group handles
        for (int l = lsub; l < L_; l += 8) {
            f32x4 v = *(const f32x4*)(xs + l * D_ + dq);
            float acc = v.x * sf.x + v.y * sf.y + v.z * sf.z + v.w * sf.w;
#pragma unroll
            for (int off = 16; off >= 1; off >>= 1)
                acc += __shfl_xor(acc, off);  // offsets <32 stay in the 32-group
            if ((tid & 31) == 0) score_s[l] = acc;
        }
    }
    __syncthreads();

    // ---- softmax over L=50 in wave 0; mask applied AFTER softmax (per ref) ----
    if (tid < 64) {
        const int l = tid;
        float s = (l < L_) ? score_s[l] : -INFINITY;
        float m = s;
#pragma unroll
        for (int off = 32; off >= 1; off >>= 1) m = fmaxf(m, __shfl_xor(m, off));
        float e = (l < L_) ? __expf(s - m) : 0.f;
        float sum = e;
#pragma unroll
        for (int off = 32; off >= 1; off >>= 1) sum += __shfl_xor(sum, off);
        if (l < L_) {
            int mk = mask[(size_t)n * L_ + l];
            w_s[l] = mk ? (e / sum) : 0.f;
        }
    }
    __syncthreads();

    // ---- pooled[d] = sum_l w[l] * x[l][d] ----
    // Lanes read d-contiguous words: 64 lanes -> 2 words/bank = free aliasing.
    if (tid < D_) {
        float acc = 0.f;
#pragma unroll
        for (int l = 0; l < L_; ++l) acc += w_s[l] * xs[l * D_ + tid];
        out[(size_t)n * D_ + tid] = acc;
    }
}

extern "C" void kernel_launch(void* const* d_in, const int* in_sizes, int n_in,
                              void* d_out, int out_size, void* d_ws, size_t ws_size,
                              hipStream_t stream) {
    // setup_inputs() order:
    //   0: friend_diff_x [N,L,D] fp32
    //   1: self_x        [B,D]   fp32
    //   2: friend_num_src (python int -> 1-elem)      [unused: F=64 static]
    //   3: friend_num_src_tensor [B] int64            [unused: uniform counts]
    //   4: friend_diff_src_mask  [N,L] int32 (bool)
    const float* x     = (const float*)d_in[0];
    const float* selfx = (const float*)d_in[1];
    const int*   mask  = (const int*)d_in[4];
    float*       out   = (float*)d_out;

    FRIENDATTN_67680094650650_kernel<<<N_, 256, 0, stream>>>(x, selfx, mask, out);
}

// Round 3
// 545.230 us; speedup vs baseline: 1.0070x; 1.0070x over previous
//
#include <hip/hip_runtime.h>
#include <math.h>

// Problem shape (fixed by reference): B=256 users, F=64 friends/user,
// L=50 history, D=128 dims, N=B*F=16384 friend rows.
// Dtypes (confirmed round 2): all float tensors fp32; mask int32; out fp32.
constexpr int B_ = 256;
constexpr int F_ = 64;
constexpr int L_ = 50;
constexpr int D_ = 128;
constexpr int N_ = B_ * F_;
constexpr int CHUNKS = (L_ * D_) / 4;  // 1600 16-byte chunks per row tile

typedef float f32x4 __attribute__((ext_vector_type(4)));

// Async global->LDS DMA, 16 B per lane. LDS dest must be wave-uniform base;
// lane i's data lands at ldsbase + i*16 (m104/m108). Our flat tile layout
// matches exactly: chunk (cbase+lane) lives at xs + (cbase+lane)*4 floats.
__device__ __forceinline__ void load_lds16(const float* g, float* lds) {
    __builtin_amdgcn_global_load_lds(
        (const __attribute__((address_space(1))) void*)g,
        (__attribute__((address_space(3))) void*)lds, 16, 0, 0);
}

__global__ __launch_bounds__(256) void FRIENDATTN_67680094650650_kernel(
    const float* __restrict__ x,      // [N, L, D] fp32
    const float* __restrict__ selfx,  // [B, D]    fp32
    const int* __restrict__ mask,     // [N, L]    int32 0/1
    float* __restrict__ out)          // [N, D]    fp32
{
    __shared__ __align__(16) float xs[L_ * D_];  // 25600 B -> 6 blocks/CU
    __shared__ float score_s[L_];
    __shared__ float w_s[L_];

    const int tid  = threadIdx.x;
    const int lane = tid & 63;
    const int w    = tid >> 6;  // wave 0..3
    const int n    = blockIdx.x;
    const int b    = n >> 6;    // n / F_

    // ---- stage x row via async DMA: 6 (7 for wave 0) independent in-flight
    // 1-KB-per-wave transfers, no VGPR round-trip, single drain at barrier ----
    const float* xrow = x + (size_t)n * (L_ * D_);
#pragma unroll
    for (int i = 0; i < 6; ++i) {
        const int cbase = i * 256 + w * 64;  // wave-uniform chunk base
        load_lds16(xrow + (size_t)(cbase + lane) * 4, xs + cbase * 4);
    }
    if (w == 0) {  // tail: chunks 1536..1599
        load_lds16(xrow + (size_t)(1536 + lane) * 4, xs + 1536 * 4);
    }

    // ---- overlap with DMA: self fragment + mask (independent loads) ----
    const int dq = (tid & 31) * 4;  // d-offset; lanes 0..31 cover d=0..127
    const f32x4 sf = *(const f32x4*)(selfx + b * D_ + dq);
    int mk = 1;
    if (tid < L_) mk = mask[(size_t)n * L_ + tid];

    __syncthreads();  // drains vmcnt(0): DMA complete, tile resident

    // ---- scores: 32-lane groups cooperate per l-row (contiguous b128 reads,
    // conflict-free) ----
    {
        const int lsub = tid >> 5;  // 0..7
        for (int l = lsub; l < L_; l += 8) {
            f32x4 v = *(const f32x4*)(xs + l * D_ + dq);
            float acc = v.x * sf.x + v.y * sf.y + v.z * sf.z + v.w * sf.w;
#pragma unroll
            for (int off = 16; off >= 1; off >>= 1)
                acc += __shfl_xor(acc, off);  // stays within the 32-group
            if ((tid & 31) == 0) score_s[l] = acc;
        }
    }
    __syncthreads();

    // ---- softmax over L=50 in wave 0; mask applied AFTER softmax (per ref) ----
    if (tid < 64) {
        const int l = tid;
        float s = (l < L_) ? score_s[l] : -INFINITY;
        float m = s;
#pragma unroll
        for (int off = 32; off >= 1; off >>= 1) m = fmaxf(m, __shfl_xor(m, off));
        float e = (l < L_) ? __expf(s - m) : 0.f;
        float sum = e;
#pragma unroll
        for (int off = 32; off >= 1; off >>= 1) sum += __shfl_xor(sum, off);
        if (l < L_) w_s[l] = mk ? (e / sum) : 0.f;
    }
    __syncthreads();

    // ---- pooled[d] = sum_l w[l] * x[l][d]; 64 lanes over 32 banks = 2-way
    // aliasing (free); independent reads pipeline ----
    if (tid < D_) {
        float acc = 0.f;
#pragma unroll
        for (int l = 0; l < L_; ++l) acc += w_s[l] * xs[l * D_ + tid];
        out[(size_t)n * D_ + tid] = acc;
    }
}

extern "C" void kernel_launch(void* const* d_in, const int* in_sizes, int n_in,
                              void* d_out, int out_size, void* d_ws, size_t ws_size,
                              hipStream_t stream) {
    // setup_inputs() order:
    //   0: friend_diff_x [N,L,D] fp32
    //   1: self_x        [B,D]   fp32
    //   2: friend_num_src (python int)                 [unused: F=64 static]
    //   3: friend_num_src_tensor [B]                   [unused: uniform counts]
    //   4: friend_diff_src_mask  [N,L] int32 (bool)
    const float* x     = (const float*)d_in[0];
    const float* selfx = (const float*)d_in[1];
    const int*   mask  = (const int*)d_in[4];
    float*       out   = (float*)d_out;

    FRIENDATTN_67680094650650_kernel<<<N_, 256, 0, stream>>>(x, selfx, mask, out);
}

// Round 4
// 543.137 us; speedup vs baseline: 1.0109x; 1.0039x over previous
//
#include <hip/hip_runtime.h>
#include <math.h>

// Problem shape (fixed by reference): B=256 users, F=64 friends/user,
// L=50 history, D=128 dims, N=B*F=16384 friend rows.
// Dtypes (confirmed round 2): all float tensors fp32; mask int32; out fp32.
//
// Round-4 structure: register-resident row slice, NO LDS tile.
// Chunk c = tid + 256k  (c in [0,1600), 16 B each) maps to
//   l  = c/32  = tid/32 + 8k   (exact: 256/32 = 8)
//   dc = (c%32)*4 = (tid%32)*4 (thread's FIXED d-slice)
// so the 32 threads holding a given l are one contiguous 32-lane shfl group,
// and each x element is consumed twice (score, pooling) straight from VGPRs.
constexpr int B_ = 256;
constexpr int F_ = 64;
constexpr int L_ = 50;
constexpr int D_ = 128;
constexpr int N_ = B_ * F_;

typedef float f32x4 __attribute__((ext_vector_type(4)));

__global__ __launch_bounds__(256) void FRIENDATTN_67680094650650_kernel(
    const float* __restrict__ x,      // [N, L, D] fp32
    const float* __restrict__ selfx,  // [B, D]    fp32
    const int* __restrict__ mask,     // [N, L]    int32 0/1
    float* __restrict__ out)          // [N, D]    fp32
{
    __shared__ float score_s[L_];
    __shared__ float w_s[L_];
    __shared__ __align__(16) float pool[4][D_];  // per-wave pooling partials, 2 KB

    const int tid = threadIdx.x;
    const int n   = blockIdx.x;
    const int b   = n >> 6;        // n / F_
    const int g   = tid >> 5;      // 32-group id 0..7  -> l = g + 8k
    const int r   = tid & 31;      // rank in group
    const int dc  = r * 4;         // this thread's d-slice [dc, dc+4)

    const float* xrow = x + (size_t)n * (L_ * D_);

    // ---- issue all global loads up front: 6 (7 for tid<64) independent
    // coalesced float4 loads per thread; row lives in ~28 VGPRs ----
    f32x4 v[7];
#pragma unroll
    for (int k = 0; k < 6; ++k)
        v[k] = *(const f32x4*)(xrow + (size_t)(tid + 256 * k) * 4);
    const bool has7 = tid < 64;    // tail chunks 1536..1599 -> l = g+48
    if (has7) v[6] = *(const f32x4*)(xrow + (size_t)(tid + 1536) * 4);

    const f32x4 sf = *(const f32x4*)(selfx + b * D_ + dc);
    int mk = 1;
    if (tid < L_) mk = mask[(size_t)n * L_ + tid];  // all in wave 0

    // ---- scores: per chunk, 4-wide dot + 5 shfl_xor within the 32-group ----
#pragma unroll
    for (int k = 0; k < 6; ++k) {
        float acc = v[k].x * sf.x + v[k].y * sf.y + v[k].z * sf.z + v[k].w * sf.w;
#pragma unroll
        for (int off = 16; off >= 1; off >>= 1) acc += __shfl_xor(acc, off);
        if (r == 0) score_s[g + 8 * k] = acc;
    }
    if (has7) {
        float acc = v[6].x * sf.x + v[6].y * sf.y + v[6].z * sf.z + v[6].w * sf.w;
#pragma unroll
        for (int off = 16; off >= 1; off >>= 1) acc += __shfl_xor(acc, off);
        if (r == 0) score_s[g + 48] = acc;  // g in {0,1} here -> l = 48,49
    }
    __syncthreads();

    // ---- softmax over L=50 in wave 0; mask applied AFTER softmax (per ref) ----
    if (tid < 64) {
        const int l = tid;
        float s = (l < L_) ? score_s[l] : -INFINITY;
        float m = s;
#pragma unroll
        for (int off = 32; off >= 1; off >>= 1) m = fmaxf(m, __shfl_xor(m, off));
        float e = (l < L_) ? __expf(s - m) : 0.f;
        float sum = e;
#pragma unroll
        for (int off = 32; off >= 1; off >>= 1) sum += __shfl_xor(sum, off);
        if (l < L_) w_s[l] = mk ? (e / sum) : 0.f;
    }
    __syncthreads();

    // ---- pooling from registers: p[dc..dc+3] = sum over this thread's l's ----
    // w_s reads broadcast within each 32-group (same address) -> conflict-free.
    f32x4 p = {0.f, 0.f, 0.f, 0.f};
#pragma unroll
    for (int k = 0; k < 6; ++k) {
        const float wl = w_s[g + 8 * k];
        p.x += wl * v[k].x; p.y += wl * v[k].y;
        p.z += wl * v[k].z; p.w += wl * v[k].w;
    }
    if (has7) {
        const float wl = w_s[g + 48];
        p.x += wl * v[6].x; p.y += wl * v[6].y;
        p.z += wl * v[6].z; p.w += wl * v[6].w;
    }
    // pair-reduce groups g and g^1 (same wave, same dc) with one xor-32 shfl
    p.x += __shfl_xor(p.x, 32); p.y += __shfl_xor(p.y, 32);
    p.z += __shfl_xor(p.z, 32); p.w += __shfl_xor(p.w, 32);
    const int wv = tid >> 6;  // wave 0..3
    if ((tid & 63) < 32) *(f32x4*)(&pool[wv][dc]) = p;  // b128, conflict-free
    __syncthreads();

    // ---- final: sum 4 wave-partials per d, coalesced store ----
    if (tid < D_) {
        out[(size_t)n * D_ + tid] =
            pool[0][tid] + pool[1][tid] + pool[2][tid] + pool[3][tid];
    }
}

extern "C" void kernel_launch(void* const* d_in, const int* in_sizes, int n_in,
                              void* d_out, int out_size, void* d_ws, size_t ws_size,
                              hipStream_t stream) {
    // setup_inputs() order:
    //   0: friend_diff_x [N,L,D] fp32
    //   1: self_x        [B,D]   fp32
    //   2: friend_num_src (python int)                 [unused: F=64 static]
    //   3: friend_num_src_tensor [B]                   [unused: uniform counts]
    //   4: friend_diff_src_mask  [N,L] int32 (bool)
    const float* x     = (const float*)d_in[0];
    const float* selfx = (const float*)d_in[1];
    const int*   mask  = (const int*)d_in[4];
    float*       out   = (float*)d_out;

    FRIENDATTN_67680094650650_kernel<<<N_, 256, 0, stream>>>(x, selfx, mask, out);
}